// Round 1
// baseline (656.443 us; speedup 1.0000x reference)
//
#include <hip/hip_runtime.h>
#include <cstddef>

// ============================================================================
// MaskedMultiHeadAttention (B=4,S=2048,DM=1024,H=16,HD=64), faithful to ref:
//   softmax over the QUERY axis (axis=2), then /sqrt(HD); mask is a no-op.
// Pipeline (bf16 MFMA everywhere, fp32 accum):
//   1) wt_kernel x4 : W[k][n] f32 -> WT[n][k] bf16   (gemm_bt wants B^T)
//   2) gemm_bt<0>   : Q = queries@Wq+bq -> [b,h,s,d] bf16
//      gemm_bt<0>   : K -> [b,h,s,d] bf16
//      gemm_bt<2>   : V -> [b,h,d,s] bf16 (transposed for PV B-fragments)
//   3) stats_kernel : per-column m[k], 1/(8*l[k]) of softmax over q
//   4) attn_kernel  : S-tile MFMA -> P=exp(S-m)*scale via LDS roundtrip -> PV
//   5) gemm_bt<1>   : out = Hout@Wo+bo -> fp32 d_out
// Workspace: needs ~73 MB (Qb/Kb/Vt/Hout 16MB each + 4x2MB WT + 1MB stats).
// ============================================================================

typedef unsigned short u16t;
typedef __attribute__((ext_vector_type(8))) short short8;
typedef __attribute__((ext_vector_type(4))) float floatx4;

#define MFMA16(a, b, c) __builtin_amdgcn_mfma_f32_16x16x32_bf16((a), (b), (c), 0, 0, 0)
#define GLDS16(g, l)                                                        \
  __builtin_amdgcn_global_load_lds(                                         \
      (const __attribute__((address_space(1))) unsigned int*)(g),           \
      (__attribute__((address_space(3))) unsigned int*)(l), 16, 0, 0)

static __device__ __forceinline__ u16t f2bf(float f) {
  union { float f; unsigned u; } v; v.f = f;
  unsigned r = v.u + 0x7FFFu + ((v.u >> 16) & 1u);  // RNE
  return (u16t)(r >> 16);
}
static __device__ __forceinline__ float bf2f(u16t h) {
  union { unsigned u; float f; } v; v.u = ((unsigned)h) << 16;
  return v.f;
}

#define SEQ    2048
#define NHEAD  16
#define HDIM   64
#define DMODEL 1024
#define MROWS  8192  // B*S

// ---------------------------------------------------------------------------
// W [1024][1024] f32 (in,out) -> WT [n][k] bf16. Each thread packs 4 k's.
__global__ __launch_bounds__(256) void wt_kernel(const float* __restrict__ W,
                                                 u16t* __restrict__ WT) {
  int id = blockIdx.x * 256 + threadIdx.x;  // (1024/4)*1024 ids
  int k = (id >> 10) << 2;
  int n = id & 1023;
  unsigned a0 = f2bf(W[(size_t)k * 1024 + n]);
  unsigned a1 = f2bf(W[(size_t)(k + 1) * 1024 + n]);
  unsigned a2 = f2bf(W[(size_t)(k + 2) * 1024 + n]);
  unsigned a3 = f2bf(W[(size_t)(k + 3) * 1024 + n]);
  uint2 p; p.x = a0 | (a1 << 16); p.y = a2 | (a3 << 16);
  *(uint2*)&WT[(size_t)n * 1024 + k] = p;
}

// ---------------------------------------------------------------------------
// C[8192,1024] = A[8192,1024] * BT[1024,1024]^T + bias
// MODE 0: A fp32 (cvt fused in staging), out bf16 scattered [b,h,s,d]
// MODE 1: A bf16 (global_load_lds),      out fp32 flat [m,n]
// MODE 2: A fp32,                        out bf16 scattered [b,h,d,s]
template <int MODE>
__global__ __launch_bounds__(256)
void gemm_bt(const void* __restrict__ Ap, const u16t* __restrict__ BT,
             const float* __restrict__ bias, void* __restrict__ Cp) {
  constexpr int K = 1024;
  __shared__ __align__(16) u16t lA[128 * 64];
  __shared__ __align__(16) u16t lB[128 * 64];
  const int tid = threadIdx.x;
  const int lane = tid & 63, w = tid >> 6;
  const int wm = w >> 1, wn = w & 1;
  const int lrow = lane & 15, lq = lane >> 4;
  const int m0 = blockIdx.y * 128, n0 = blockIdx.x * 128;

  floatx4 acc[4][4];
#pragma unroll
  for (int i = 0; i < 4; ++i)
#pragma unroll
    for (int j = 0; j < 4; ++j) acc[i][j] = {0.f, 0.f, 0.f, 0.f};

  for (int kb = 0; kb < K; kb += 64) {
    if constexpr (MODE == 1) {
      const u16t* Ag = (const u16t*)Ap;
#pragma unroll
      for (int i = 0; i < 4; ++i) {
        int chunk = w * 4 + i;
        int off = chunk * 1024 + lane * 16;  // byte offset in 16KB tile
        int r = off >> 7, ib = off & 127;
        GLDS16(Ag + (size_t)(m0 + r) * K + kb + (ib >> 1), &lA[chunk * 512]);
      }
    } else {
      const float* Ag = (const float*)Ap;
#pragma unroll
      for (int i = 0; i < 8; ++i) {
        int e = (i * 256 + tid) * 4;  // element in 128x64 tile
        int r = e >> 6, c = e & 63;
        const float* src = Ag + (size_t)(m0 + r) * K + kb + c;
        uint2 p;
        p.x = (unsigned)f2bf(src[0]) | ((unsigned)f2bf(src[1]) << 16);
        p.y = (unsigned)f2bf(src[2]) | ((unsigned)f2bf(src[3]) << 16);
        *(uint2*)&lA[r * 64 + c] = p;
      }
    }
#pragma unroll
    for (int i = 0; i < 4; ++i) {
      int chunk = w * 4 + i;
      int off = chunk * 1024 + lane * 16;
      int r = off >> 7, ib = off & 127;
      GLDS16(BT + (size_t)(n0 + r) * K + kb + (ib >> 1), &lB[chunk * 512]);
    }
    __syncthreads();
#pragma unroll
    for (int kk = 0; kk < 2; ++kk) {
      short8 af[4], bfr[4];
#pragma unroll
      for (int t = 0; t < 4; ++t)
        af[t] = *(const short8*)&lA[(wm * 64 + t * 16 + lrow) * 64 + kk * 32 + lq * 8];
#pragma unroll
      for (int t = 0; t < 4; ++t)
        bfr[t] = *(const short8*)&lB[(wn * 64 + t * 16 + lrow) * 64 + kk * 32 + lq * 8];
#pragma unroll
      for (int i = 0; i < 4; ++i)
#pragma unroll
        for (int j = 0; j < 4; ++j)
          acc[i][j] = MFMA16(af[i], bfr[j], acc[i][j]);
    }
    __syncthreads();
  }

#pragma unroll
  for (int j = 0; j < 4; ++j) {
    int cg = n0 + wn * 64 + j * 16 + lrow;
    float bv = bias[cg];
#pragma unroll
    for (int i = 0; i < 4; ++i) {
#pragma unroll
      for (int r = 0; r < 4; ++r) {
        int rg = m0 + wm * 64 + i * 16 + lq * 4 + r;  // C/D: row=(lane>>4)*4+reg
        float v = acc[i][j][r] + bv;
        if constexpr (MODE == 1) {
          ((float*)Cp)[(size_t)rg * 1024 + cg] = v;
        } else {
          int b = rg >> 11, s = rg & 2047;
          int h = cg >> 6, d = cg & 63;
          size_t bh = (size_t)(b * NHEAD + h);
          if constexpr (MODE == 0)
            ((u16t*)Cp)[(bh * SEQ + s) * HDIM + d] = f2bf(v);
          else
            ((u16t*)Cp)[(bh * HDIM + d) * SEQ + s] = f2bf(v);
        }
      }
    }
  }
}

// ---------------------------------------------------------------------------
// Column-softmax stats: for each (b,h,k): m[k]=max_q S, ss[k]=1/(8*sum_q exp).
// Block: (256-col chunk) x (b*h). Wave w owns cols [w*64, w*64+64).
__global__ __launch_bounds__(256)
void stats_kernel(const u16t* __restrict__ Qb, const u16t* __restrict__ Kb,
                  float* __restrict__ sm, float* __restrict__ ss) {
  __shared__ __align__(16) u16t lK[256 * 64];
  __shared__ __align__(16) u16t lQ[128 * 64];
  const int tid = threadIdx.x, lane = tid & 63, w = tid >> 6;
  const int lrow = lane & 15, lq = lane >> 4;
  const int bh = blockIdx.y;
  const int c0 = blockIdx.x * 256;
  const u16t* Kbase = Kb + (size_t)bh * (SEQ * HDIM);
  const u16t* Qbase = Qb + (size_t)bh * (SEQ * HDIM);

  // K chunk is contiguous 32KB: 32 x 1KB chunks, 8 per wave
#pragma unroll
  for (int i = 0; i < 8; ++i) {
    int chunk = w * 8 + i;
    GLDS16(Kbase + (size_t)c0 * HDIM + chunk * 512 + lane * 8, &lK[chunk * 512]);
  }

  float mcur[4], lcur[4];
#pragma unroll
  for (int t = 0; t < 4; ++t) { mcur[t] = -1e30f; lcur[t] = 0.f; }

  for (int q0 = 0; q0 < SEQ; q0 += 128) {
#pragma unroll
    for (int i = 0; i < 4; ++i) {
      int chunk = w * 4 + i;
      GLDS16(Qbase + (size_t)q0 * HDIM + chunk * 512 + lane * 8, &lQ[chunk * 512]);
    }
    __syncthreads();
#pragma unroll
    for (int nt = 0; nt < 4; ++nt) {
      short8 bf0 = *(const short8*)&lK[(w * 64 + nt * 16 + lrow) * 64 + lq * 8];
      short8 bf1 = *(const short8*)&lK[(w * 64 + nt * 16 + lrow) * 64 + lq * 8 + 32];
      float mm = mcur[nt], ll = lcur[nt];
#pragma unroll
      for (int mt = 0; mt < 8; ++mt) {
        short8 af0 = *(const short8*)&lQ[(mt * 16 + lrow) * 64 + lq * 8];
        short8 af1 = *(const short8*)&lQ[(mt * 16 + lrow) * 64 + lq * 8 + 32];
        floatx4 a = {0.f, 0.f, 0.f, 0.f};
        a = MFMA16(af0, bf0, a);
        a = MFMA16(af1, bf1, a);
        float t0 = fmaxf(fmaxf(a[0], a[1]), fmaxf(a[2], a[3]));
        float mn = fmaxf(mm, t0);
        ll = ll * __expf(mm - mn) + __expf(a[0] - mn) + __expf(a[1] - mn) +
             __expf(a[2] - mn) + __expf(a[3] - mn);
        mm = mn;
      }
      mcur[nt] = mm; lcur[nt] = ll;
    }
    __syncthreads();
  }
  // lanes {l, l^16, l^32, l^48} hold disjoint q-subsets of the same column
#pragma unroll
  for (int t = 0; t < 4; ++t) {
    float mm = mcur[t], ll = lcur[t];
#pragma unroll
    for (int off = 16; off <= 32; off <<= 1) {
      float m2 = __shfl_xor(mm, off);
      float l2 = __shfl_xor(ll, off);
      float mn = fmaxf(mm, m2);
      ll = ll * __expf(mm - mn) + l2 * __expf(m2 - mn);
      mm = mn;
    }
    mcur[t] = mm; lcur[t] = ll;
  }
  if (lane < 16) {
#pragma unroll
    for (int t = 0; t < 4; ++t) {
      int col = c0 + w * 64 + t * 16 + lane;
      sm[(size_t)bh * SEQ + col] = mcur[t];
      ss[(size_t)bh * SEQ + col] = 1.f / (8.f * lcur[t]);
    }
  }
}

// ---------------------------------------------------------------------------
// attn: per (b,h, 64-q tile): loop 128-k tiles: S=QK^T (MFMA), P=exp(S-m)*ss
// via LDS roundtrip (C-layout -> A-layout), O += P*V (MFMA). Wave w owns 16 q.
__global__ __launch_bounds__(256)
void attn_kernel(const u16t* __restrict__ Qb, const u16t* __restrict__ Kb,
                 const u16t* __restrict__ Vt, const float* __restrict__ sm,
                 const float* __restrict__ ss, u16t* __restrict__ Hout) {
  __shared__ __align__(16) u16t lQ[64 * 64];
  __shared__ __align__(16) u16t lKP[128 * 64];  // K tile; reused as P[64][128]
  __shared__ __align__(16) u16t lV[64 * 128];   // V^T tile [d][k]
  __shared__ float lM[128];
  __shared__ float lS[128];
  const int tid = threadIdx.x, lane = tid & 63, w = tid >> 6;
  const int lrow = lane & 15, lq = lane >> 4;
  const int bh = blockIdx.y, q0 = blockIdx.x * 64;
  const size_t hb = (size_t)bh * (SEQ * HDIM);

  // Q tile: contiguous 8KB, 8 chunks, 2 per wave
#pragma unroll
  for (int i = 0; i < 2; ++i) {
    int chunk = w * 2 + i;
    GLDS16(Qb + hb + (size_t)q0 * HDIM + chunk * 512 + lane * 8, &lQ[chunk * 512]);
  }

  floatx4 ao[4];
#pragma unroll
  for (int t = 0; t < 4; ++t) ao[t] = {0.f, 0.f, 0.f, 0.f};

  for (int kt = 0; kt < 16; ++kt) {
    const int k0 = kt * 128;
    // K tile: contiguous 16KB
#pragma unroll
    for (int i = 0; i < 4; ++i) {
      int chunk = w * 4 + i;
      GLDS16(Kb + hb + (size_t)k0 * HDIM + chunk * 512 + lane * 8, &lKP[chunk * 512]);
    }
    // V^T tile: rows d (stride SEQ), 256B contiguous per row => 4 rows/chunk
#pragma unroll
    for (int i = 0; i < 4; ++i) {
      int chunk = w * 4 + i;
      int off = chunk * 1024 + lane * 16;
      int d = off >> 8, ib = off & 255;
      GLDS16(Vt + hb + ((size_t)d << 11) + k0 + (ib >> 1), &lV[chunk * 512]);
    }
    if (tid < 128) lM[tid] = sm[(size_t)bh * SEQ + k0 + tid];
    else           lS[tid - 128] = ss[(size_t)bh * SEQ + k0 + tid - 128];
    __syncthreads();

    // S = Q K^T : wave w computes its 16 q rows x 128 cols
    floatx4 pacc[8];
    {
      short8 af0 = *(const short8*)&lQ[(w * 16 + lrow) * 64 + lq * 8];
      short8 af1 = *(const short8*)&lQ[(w * 16 + lrow) * 64 + lq * 8 + 32];
#pragma unroll
      for (int nt = 0; nt < 8; ++nt) {
        short8 bf0 = *(const short8*)&lKP[(nt * 16 + lrow) * 64 + lq * 8];
        short8 bf1 = *(const short8*)&lKP[(nt * 16 + lrow) * 64 + lq * 8 + 32];
        floatx4 a = {0.f, 0.f, 0.f, 0.f};
        a = MFMA16(af0, bf0, a);
        a = MFMA16(af1, bf1, a);
        pacc[nt] = a;
      }
    }
    __syncthreads();  // all waves done reading K before P overwrites lKP

    // P = exp(S - m[col]) * ss[col], written in [q][k] layout (wave-local rows)
#pragma unroll
    for (int nt = 0; nt < 8; ++nt) {
      int col = nt * 16 + lrow;
      float mc = lM[col];
      float sc = lS[col];
#pragma unroll
      for (int r = 0; r < 4; ++r) {
        float p = __expf(pacc[nt][r] - mc) * sc;
        lKP[(w * 16 + lq * 4 + r) * 128 + col] = f2bf(p);
      }
    }
    // O += P * V' (wave reads only its own P rows -> no barrier needed here)
#pragma unroll
    for (int nt = 0; nt < 4; ++nt) {
#pragma unroll
      for (int kk = 0; kk < 4; ++kk) {
        short8 af = *(const short8*)&lKP[(w * 16 + lrow) * 128 + kk * 32 + lq * 8];
        short8 bf = *(const short8*)&lV[(nt * 16 + lrow) * 128 + kk * 32 + lq * 8];
        ao[nt] = MFMA16(af, bf, ao[nt]);
      }
    }
    __syncthreads();  // before next iteration restages lKP/lV
  }

  // Hout[b][q][h*64+d]
  const int b = bh >> 4, h = bh & 15;
#pragma unroll
  for (int nt = 0; nt < 4; ++nt) {
    int d = nt * 16 + lrow;
#pragma unroll
    for (int r = 0; r < 4; ++r) {
      int q = q0 + w * 16 + lq * 4 + r;
      Hout[((size_t)b * SEQ + q) * DMODEL + h * HDIM + d] = f2bf(ao[nt][r]);
    }
  }
}

// ---------------------------------------------------------------------------
extern "C" void kernel_launch(void* const* d_in, const int* in_sizes, int n_in,
                              void* d_out, int out_size, void* d_ws, size_t ws_size,
                              hipStream_t stream) {
  (void)in_sizes; (void)n_in; (void)out_size; (void)ws_size;
  const float* queries = (const float*)d_in[0];
  const float* keys    = (const float*)d_in[1];
  const float* values  = (const float*)d_in[2];
  const float* Wq = (const float*)d_in[3];
  const float* bq = (const float*)d_in[4];
  const float* Wk = (const float*)d_in[5];
  const float* bk = (const float*)d_in[6];
  const float* Wv = (const float*)d_in[7];
  const float* bv = (const float*)d_in[8];
  const float* Wo = (const float*)d_in[9];
  const float* bo = (const float*)d_in[10];

  char* ws = (char*)d_ws;
  const size_t MB = 1024 * 1024;
  u16t* Qb   = (u16t*)(ws + 0 * MB);    // [b,h,s,d] bf16, 16MB
  u16t* Kb   = (u16t*)(ws + 16 * MB);   // [b,h,s,d] bf16, 16MB
  u16t* Vt   = (u16t*)(ws + 32 * MB);   // [b,h,d,s] bf16, 16MB
  u16t* Hout = (u16t*)(ws + 48 * MB);   // [b,s,h*64+d] bf16, 16MB
  u16t* wqt  = (u16t*)(ws + 64 * MB);   // [n][k] bf16, 2MB each
  u16t* wkt  = (u16t*)(ws + 66 * MB);
  u16t* wvt  = (u16t*)(ws + 68 * MB);
  u16t* wot  = (u16t*)(ws + 70 * MB);
  float* sm  = (float*)(ws + 72 * MB);            // [bh][s] col max
  float* ss  = (float*)(ws + 72 * MB + 512 * 1024);  // [bh][s] 1/(8*l)

  wt_kernel<<<1024, 256, 0, stream>>>(Wq, wqt);
  wt_kernel<<<1024, 256, 0, stream>>>(Wk, wkt);
  wt_kernel<<<1024, 256, 0, stream>>>(Wv, wvt);
  wt_kernel<<<1024, 256, 0, stream>>>(Wo, wot);

  gemm_bt<0><<<dim3(8, 64), 256, 0, stream>>>(queries, wqt, bq, Qb);
  gemm_bt<0><<<dim3(8, 64), 256, 0, stream>>>(keys,    wkt, bk, Kb);
  gemm_bt<2><<<dim3(8, 64), 256, 0, stream>>>(values,  wvt, bv, Vt);

  stats_kernel<<<dim3(8, 64), 256, 0, stream>>>(Qb, Kb, sm, ss);
  attn_kernel<<<dim3(32, 64), 256, 0, stream>>>(Qb, Kb, Vt, sm, ss, Hout);

  gemm_bt<1><<<dim3(8, 64), 256, 0, stream>>>(Hout, wot, bo, d_out);
}

// Round 2
// 519.206 us; speedup vs baseline: 1.2643x; 1.2643x over previous
//
#include <hip/hip_runtime.h>
#include <cstddef>

// ============================================================================
// MaskedMultiHeadAttention (B=4,S=2048,DM=1024,H=16,HD=64), faithful to ref:
//   softmax over the QUERY axis (axis=2), then /sqrt(HD); mask is a no-op.
// Round 2: XOR-swizzled LDS layouts everywhere (pre-swizzled GLOBAL layouts
// for all global_load_lds-staged tensors), S^T=K*Q^T MFMA so P writes are
// conflict-free ds_write_b64. Targets the 1.1e8 SQ_LDS_BANK_CONFLICT.
// ============================================================================

typedef unsigned short u16t;
typedef __attribute__((ext_vector_type(8))) short short8;
typedef __attribute__((ext_vector_type(4))) float floatx4;

#define MFMA16(a, b, c) __builtin_amdgcn_mfma_f32_16x16x32_bf16((a), (b), (c), 0, 0, 0)
#define GLDS16(g, l)                                                        \
  __builtin_amdgcn_global_load_lds(                                         \
      (const __attribute__((address_space(1))) unsigned int*)(g),           \
      (__attribute__((address_space(3))) unsigned int*)(l), 16, 0, 0)

static __device__ __forceinline__ u16t f2bf(float f) {
  union { float f; unsigned u; } v; v.f = f;
  unsigned r = v.u + 0x7FFFu + ((v.u >> 16) & 1u);  // RNE
  return (u16t)(r >> 16);
}

// XOR swizzle within a 64- or 128-elem row block: permutes 8-elem groups by
// the low 3 bits of the row index. Breaks the 128B/256B bank periodicity.
static __device__ __forceinline__ int swz(int row, int col) {
  return (((col >> 3) ^ (row & 7)) << 3) | (col & 7);
}

#define SEQ    2048
#define NHEAD  16
#define HDIM   64
#define DMODEL 1024

// ---------------------------------------------------------------------------
// W [1024][1024] f32 (in,out) -> WT [n][k-swizzled] bf16 (key n&7 per 64-blk).
__global__ __launch_bounds__(256) void wt_kernel(const float* __restrict__ W,
                                                 u16t* __restrict__ WT) {
  int id = blockIdx.x * 256 + threadIdx.x;  // (1024/4)*1024 ids
  int k = (id >> 10) << 2;
  int n = id & 1023;
  unsigned a0 = f2bf(W[(size_t)k * 1024 + n]);
  unsigned a1 = f2bf(W[(size_t)(k + 1) * 1024 + n]);
  unsigned a2 = f2bf(W[(size_t)(k + 2) * 1024 + n]);
  unsigned a3 = f2bf(W[(size_t)(k + 3) * 1024 + n]);
  uint2 p; p.x = a0 | (a1 << 16); p.y = a2 | (a3 << 16);
  *(uint2*)&WT[(size_t)n * 1024 + (k & ~63) + swz(n, k & 63)] = p;
}

// ---------------------------------------------------------------------------
// C[8192,1024] = A[8192,1024] * BT[1024,1024]^T + bias   (BT pre-swizzled)
// MODE 0: A fp32 (cvt fused in staging), out bf16 swizzled [b,h,s,d]
// MODE 1: A bf16 swizzled (global_load_lds), out fp32 flat [m,n]
// MODE 2: A fp32,                        out bf16 swizzled [b,h,d,s]
template <int MODE>
__global__ __launch_bounds__(256)
void gemm_bt(const void* __restrict__ Ap, const u16t* __restrict__ BT,
             const float* __restrict__ bias, void* __restrict__ Cp) {
  constexpr int K = 1024;
  __shared__ __align__(16) u16t lA[128 * 64];
  __shared__ __align__(16) u16t lB[128 * 64];
  const int tid = threadIdx.x;
  const int lane = tid & 63, w = tid >> 6;
  const int wm = w >> 1, wn = w & 1;
  const int lrow = lane & 15, lq = lane >> 4;
  const int m0 = blockIdx.y * 128, n0 = blockIdx.x * 128;

  floatx4 acc[4][4];
#pragma unroll
  for (int i = 0; i < 4; ++i)
#pragma unroll
    for (int j = 0; j < 4; ++j) acc[i][j] = {0.f, 0.f, 0.f, 0.f};

  for (int kb = 0; kb < K; kb += 64) {
    if constexpr (MODE == 1) {
      const u16t* Ag = (const u16t*)Ap;
#pragma unroll
      for (int i = 0; i < 4; ++i) {
        int chunk = w * 4 + i;
        int off = chunk * 1024 + lane * 16;  // byte offset in 16KB tile
        int r = off >> 7, ib = off & 127;
        GLDS16(Ag + (size_t)(m0 + r) * K + kb + (ib >> 1), &lA[chunk * 512]);
      }
    } else {
      const float* Ag = (const float*)Ap;
#pragma unroll
      for (int i = 0; i < 8; ++i) {
        int e = (i * 256 + tid) * 4;  // element in 128x64 tile
        int r = e >> 6, c = e & 63;
        const float* src = Ag + (size_t)(m0 + r) * K + kb + c;
        uint2 p;
        p.x = (unsigned)f2bf(src[0]) | ((unsigned)f2bf(src[1]) << 16);
        p.y = (unsigned)f2bf(src[2]) | ((unsigned)f2bf(src[3]) << 16);
        *(uint2*)&lA[r * 64 + swz(r, c)] = p;
      }
    }
#pragma unroll
    for (int i = 0; i < 4; ++i) {
      int chunk = w * 4 + i;
      int off = chunk * 1024 + lane * 16;
      int r = off >> 7, ib = off & 127;
      GLDS16(BT + (size_t)(n0 + r) * K + kb + (ib >> 1), &lB[chunk * 512]);
    }
    __syncthreads();
#pragma unroll
    for (int kk = 0; kk < 2; ++kk) {
      short8 af[4], bfr[4];
#pragma unroll
      for (int t = 0; t < 4; ++t) {
        int ar = wm * 64 + t * 16 + lrow;
        af[t] = *(const short8*)&lA[ar * 64 + swz(ar, kk * 32 + lq * 8)];
      }
#pragma unroll
      for (int t = 0; t < 4; ++t) {
        int br = wn * 64 + t * 16 + lrow;
        bfr[t] = *(const short8*)&lB[br * 64 + swz(br, kk * 32 + lq * 8)];
      }
#pragma unroll
      for (int i = 0; i < 4; ++i)
#pragma unroll
        for (int j = 0; j < 4; ++j)
          acc[i][j] = MFMA16(af[i], bfr[j], acc[i][j]);
    }
    __syncthreads();
  }

#pragma unroll
  for (int j = 0; j < 4; ++j) {
    int cg = n0 + wn * 64 + j * 16 + lrow;
    float bv = bias[cg];
#pragma unroll
    for (int i = 0; i < 4; ++i) {
#pragma unroll
      for (int r = 0; r < 4; ++r) {
        int rg = m0 + wm * 64 + i * 16 + lq * 4 + r;  // C/D: row=(lane>>4)*4+reg
        float v = acc[i][j][r] + bv;
        if constexpr (MODE == 1) {
          ((float*)Cp)[(size_t)rg * 1024 + cg] = v;
        } else {
          int b = rg >> 11, s = rg & 2047;
          int h = cg >> 6, d = cg & 63;
          size_t bh = (size_t)(b * NHEAD + h);
          if constexpr (MODE == 0)
            ((u16t*)Cp)[(bh * SEQ + s) * HDIM + swz(s, d)] = f2bf(v);
          else
            ((u16t*)Cp)[(bh * HDIM + d) * SEQ + (s & ~127) + swz(d, s & 127)] = f2bf(v);
        }
      }
    }
  }
}

// ---------------------------------------------------------------------------
// Column-softmax stats: for each (b,h,k): m[k]=max_q S, ss[k]=1/(8*sum_q exp).
// Qb/Kb are swizzled (key s&7). Wave w owns cols [w*64, w*64+64).
__global__ __launch_bounds__(256)
void stats_kernel(const u16t* __restrict__ Qb, const u16t* __restrict__ Kb,
                  float* __restrict__ sm, float* __restrict__ ss) {
  __shared__ __align__(16) u16t lK[256 * 64];
  __shared__ __align__(16) u16t lQ[128 * 64];
  const int tid = threadIdx.x, lane = tid & 63, w = tid >> 6;
  const int lrow = lane & 15, lq = lane >> 4;
  const int bh = blockIdx.y;
  const int c0 = blockIdx.x * 256;
  const u16t* Kbase = Kb + (size_t)bh * (SEQ * HDIM);
  const u16t* Qbase = Qb + (size_t)bh * (SEQ * HDIM);

#pragma unroll
  for (int i = 0; i < 8; ++i) {
    int chunk = w * 8 + i;
    GLDS16(Kbase + (size_t)c0 * HDIM + chunk * 512 + lane * 8, &lK[chunk * 512]);
  }

  float mcur[4], lcur[4];
#pragma unroll
  for (int t = 0; t < 4; ++t) { mcur[t] = -1e30f; lcur[t] = 0.f; }

  for (int q0 = 0; q0 < SEQ; q0 += 128) {
#pragma unroll
    for (int i = 0; i < 4; ++i) {
      int chunk = w * 4 + i;
      GLDS16(Qbase + (size_t)q0 * HDIM + chunk * 512 + lane * 8, &lQ[chunk * 512]);
    }
    __syncthreads();
#pragma unroll
    for (int nt = 0; nt < 4; ++nt) {
      int kr = w * 64 + nt * 16 + lrow;
      short8 bf0 = *(const short8*)&lK[kr * 64 + swz(kr, lq * 8)];
      short8 bf1 = *(const short8*)&lK[kr * 64 + swz(kr, lq * 8 + 32)];
      float mm = mcur[nt], ll = lcur[nt];
#pragma unroll
      for (int mt = 0; mt < 8; ++mt) {
        int qr = mt * 16 + lrow;
        short8 af0 = *(const short8*)&lQ[qr * 64 + swz(qr, lq * 8)];
        short8 af1 = *(const short8*)&lQ[qr * 64 + swz(qr, lq * 8 + 32)];
        floatx4 a = {0.f, 0.f, 0.f, 0.f};
        a = MFMA16(af0, bf0, a);
        a = MFMA16(af1, bf1, a);
        float t0 = fmaxf(fmaxf(a[0], a[1]), fmaxf(a[2], a[3]));
        float mn = fmaxf(mm, t0);
        ll = ll * __expf(mm - mn) + __expf(a[0] - mn) + __expf(a[1] - mn) +
             __expf(a[2] - mn) + __expf(a[3] - mn);
        mm = mn;
      }
      mcur[nt] = mm; lcur[nt] = ll;
    }
    __syncthreads();
  }
#pragma unroll
  for (int t = 0; t < 4; ++t) {
    float mm = mcur[t], ll = lcur[t];
#pragma unroll
    for (int off = 16; off <= 32; off <<= 1) {
      float m2 = __shfl_xor(mm, off);
      float l2 = __shfl_xor(ll, off);
      float mn = fmaxf(mm, m2);
      ll = ll * __expf(mm - mn) + l2 * __expf(m2 - mn);
      mm = mn;
    }
    mcur[t] = mm; lcur[t] = ll;
  }
  if (lane < 16) {
#pragma unroll
    for (int t = 0; t < 4; ++t) {
      int col = c0 + w * 64 + t * 16 + lane;
      sm[(size_t)bh * SEQ + col] = mcur[t];
      ss[(size_t)bh * SEQ + col] = 1.f / (8.f * lcur[t]);
    }
  }
}

// ---------------------------------------------------------------------------
// attn: per (b,h, 64-q tile): loop 128-k tiles:
//   S^T = K*Q^T (MFMA, so each lane holds 4 k-consecutive values) ->
//   P = exp(S-m[k])*ss[k] packed to b64 LDS writes -> O += P*V (MFMA).
__global__ __launch_bounds__(256)
void attn_kernel(const u16t* __restrict__ Qb, const u16t* __restrict__ Kb,
                 const u16t* __restrict__ Vt, const float* __restrict__ sm,
                 const float* __restrict__ ss, u16t* __restrict__ Hout) {
  __shared__ __align__(16) u16t lQ[64 * 64];
  __shared__ __align__(16) u16t lKP[128 * 64];  // K tile; reused as P[64][128]
  __shared__ __align__(16) u16t lV[64 * 128];   // V^T tile [d][k]
  __shared__ __align__(16) float lM[128];
  __shared__ __align__(16) float lS[128];
  const int tid = threadIdx.x, lane = tid & 63, w = tid >> 6;
  const int lrow = lane & 15, lq = lane >> 4;
  const int bh = blockIdx.y, q0 = blockIdx.x * 64;
  const size_t hb = (size_t)bh * (SEQ * HDIM);

#pragma unroll
  for (int i = 0; i < 2; ++i) {
    int chunk = w * 2 + i;
    GLDS16(Qb + hb + (size_t)q0 * HDIM + chunk * 512 + lane * 8, &lQ[chunk * 512]);
  }

  floatx4 ao[4];
#pragma unroll
  for (int t = 0; t < 4; ++t) ao[t] = {0.f, 0.f, 0.f, 0.f};

  for (int kt = 0; kt < 16; ++kt) {
    const int k0 = kt * 128;
#pragma unroll
    for (int i = 0; i < 4; ++i) {
      int chunk = w * 4 + i;
      GLDS16(Kb + hb + (size_t)k0 * HDIM + chunk * 512 + lane * 8, &lKP[chunk * 512]);
    }
#pragma unroll
    for (int i = 0; i < 4; ++i) {
      int chunk = w * 4 + i;
      int off = chunk * 1024 + lane * 16;
      int d = off >> 8, ib = off & 255;
      GLDS16(Vt + hb + ((size_t)d << 11) + k0 + (ib >> 1), &lV[chunk * 512]);
    }
    if (tid < 128) lM[tid] = sm[(size_t)bh * SEQ + k0 + tid];
    else           lS[tid - 128] = ss[(size_t)bh * SEQ + k0 + tid - 128];
    __syncthreads();

    // S^T = K Q^T : wave w owns q-block w; lane holds St[k=nt*16+lq*4+r][q]
    floatx4 st[8];
    {
      int qr = w * 16 + lrow;
      short8 bq0 = *(const short8*)&lQ[qr * 64 + swz(qr, lq * 8)];
      short8 bq1 = *(const short8*)&lQ[qr * 64 + swz(qr, lq * 8 + 32)];
#pragma unroll
      for (int nt = 0; nt < 8; ++nt) {
        int kr = nt * 16 + lrow;
        short8 ak0 = *(const short8*)&lKP[kr * 64 + swz(kr, lq * 8)];
        short8 ak1 = *(const short8*)&lKP[kr * 64 + swz(kr, lq * 8 + 32)];
        floatx4 a = {0.f, 0.f, 0.f, 0.f};
        a = MFMA16(ak0, bq0, a);
        a = MFMA16(ak1, bq1, a);
        st[nt] = a;
      }
    }
    __syncthreads();  // all waves done reading lKP(K) before P overwrites it

    // P[q][k] = exp(St-m[k])*ss[k]; 4 k-consecutive vals -> one b64 write
#pragma unroll
    for (int nt = 0; nt < 8; ++nt) {
      int kbase = nt * 16 + lq * 4;
      float4 mv = *(const float4*)&lM[kbase];
      float4 sv = *(const float4*)&lS[kbase];
      unsigned p0 = f2bf(__expf(st[nt][0] - mv.x) * sv.x);
      unsigned p1 = f2bf(__expf(st[nt][1] - mv.y) * sv.y);
      unsigned p2 = f2bf(__expf(st[nt][2] - mv.z) * sv.z);
      unsigned p3 = f2bf(__expf(st[nt][3] - mv.w) * sv.w);
      uint2 pk; pk.x = p0 | (p1 << 16); pk.y = p2 | (p3 << 16);
      int qr = w * 16 + lrow;
      *(uint2*)&lKP[qr * 128 + swz(qr, kbase)] = pk;
    }
    // O += P * V' (wave reads only its own P rows -> no barrier needed here)
    {
      int qr = w * 16 + lrow;
      short8 ap[4];
#pragma unroll
      for (int kk = 0; kk < 4; ++kk)
        ap[kk] = *(const short8*)&lKP[qr * 128 + swz(qr, kk * 32 + lq * 8)];
#pragma unroll
      for (int nt = 0; nt < 4; ++nt) {
        int vr = nt * 16 + lrow;
#pragma unroll
        for (int kk = 0; kk < 4; ++kk) {
          short8 bv = *(const short8*)&lV[vr * 128 + swz(vr, kk * 32 + lq * 8)];
          ao[nt] = MFMA16(ap[kk], bv, ao[nt]);
        }
      }
    }
    __syncthreads();  // before next iteration restages lKP/lV
  }

  // Hout[b][q][h*64+d], swizzled (key q&7) for gemm_bt<1>'s GLDS16 staging
  const int b = bh >> 4, h = bh & 15;
#pragma unroll
  for (int nt = 0; nt < 4; ++nt) {
    int d = nt * 16 + lrow;
#pragma unroll
    for (int r = 0; r < 4; ++r) {
      int q = q0 + w * 16 + lq * 4 + r;
      Hout[((size_t)b * SEQ + q) * DMODEL + h * HDIM + swz(q, d)] = f2bf(ao[nt][r]);
    }
  }
}

// ---------------------------------------------------------------------------
extern "C" void kernel_launch(void* const* d_in, const int* in_sizes, int n_in,
                              void* d_out, int out_size, void* d_ws, size_t ws_size,
                              hipStream_t stream) {
  (void)in_sizes; (void)n_in; (void)out_size; (void)ws_size;
  const float* queries = (const float*)d_in[0];
  const float* keys    = (const float*)d_in[1];
  const float* values  = (const float*)d_in[2];
  const float* Wq = (const float*)d_in[3];
  const float* bq = (const float*)d_in[4];
  const float* Wk = (const float*)d_in[5];
  const float* bk = (const float*)d_in[6];
  const float* Wv = (const float*)d_in[7];
  const float* bv = (const float*)d_in[8];
  const float* Wo = (const float*)d_in[9];
  const float* bo = (const float*)d_in[10];

  char* ws = (char*)d_ws;
  const size_t MB = 1024 * 1024;
  u16t* Qb   = (u16t*)(ws + 0 * MB);    // [b,h,s,d] bf16 swizzled, 16MB
  u16t* Kb   = (u16t*)(ws + 16 * MB);   // [b,h,s,d] bf16 swizzled, 16MB
  u16t* Vt   = (u16t*)(ws + 32 * MB);   // [b,h,d,s] bf16 swizzled, 16MB
  u16t* Hout = (u16t*)(ws + 48 * MB);   // [b,s,dm] bf16 swizzled, 16MB
  u16t* wqt  = (u16t*)(ws + 64 * MB);   // [n][k] bf16 swizzled, 2MB each
  u16t* wkt  = (u16t*)(ws + 66 * MB);
  u16t* wvt  = (u16t*)(ws + 68 * MB);
  u16t* wot  = (u16t*)(ws + 70 * MB);
  float* sm  = (float*)(ws + 72 * MB);            // [bh][s] col max
  float* ss  = (float*)(ws + 72 * MB + 512 * 1024);  // [bh][s] 1/(8*l)

  wt_kernel<<<1024, 256, 0, stream>>>(Wq, wqt);
  wt_kernel<<<1024, 256, 0, stream>>>(Wk, wkt);
  wt_kernel<<<1024, 256, 0, stream>>>(Wv, wvt);
  wt_kernel<<<1024, 256, 0, stream>>>(Wo, wot);

  gemm_bt<0><<<dim3(8, 64), 256, 0, stream>>>(queries, wqt, bq, Qb);
  gemm_bt<0><<<dim3(8, 64), 256, 0, stream>>>(keys,    wkt, bk, Kb);
  gemm_bt<2><<<dim3(8, 64), 256, 0, stream>>>(values,  wvt, bv, Vt);

  stats_kernel<<<dim3(8, 64), 256, 0, stream>>>(Qb, Kb, sm, ss);
  attn_kernel<<<dim3(32, 64), 256, 0, stream>>>(Qb, Kb, Vt, sm, ss, Hout);

  gemm_bt<1><<<dim3(8, 64), 256, 0, stream>>>(Hout, wot, bo, d_out);
}

// Round 3
// 443.057 us; speedup vs baseline: 1.4816x; 1.1719x over previous
//
#include <hip/hip_runtime.h>
#include <cstddef>

// ============================================================================
// MaskedMultiHeadAttention (B=4,S=2048,DM=1024,H=16,HD=64), faithful to ref:
//   softmax over the QUERY axis (axis=2), then /sqrt(HD); mask is a no-op.
// Round 3: exp2-domain softmax without max (Q pre-scaled by 1/ln2; S' bounded
// so 2^S' never overflows), 1/(8*sum) folded into V rows, v_perm bf16 packing,
// attn LDS 41KB->32KB (Q frags in regs), stats re-grid, 6 launches total.
// Order: wt -> QK proj (z=2) -> stats -> V proj (scaled) -> attn -> out proj.
// ============================================================================

typedef unsigned short u16t;
typedef __attribute__((ext_vector_type(8))) short short8;
typedef __attribute__((ext_vector_type(4))) float floatx4;

#define MFMA16(a, b, c) __builtin_amdgcn_mfma_f32_16x16x32_bf16((a), (b), (c), 0, 0, 0)
#define GLDS16(g, l)                                                        \
  __builtin_amdgcn_global_load_lds(                                         \
      (const __attribute__((address_space(1))) unsigned int*)(g),           \
      (__attribute__((address_space(3))) unsigned int*)(l), 16, 0, 0)

#if __has_builtin(__builtin_amdgcn_exp2f)
#define EXP2(x) __builtin_amdgcn_exp2f(x)
#else
#define EXP2(x) __expf(0.69314718f * (x))
#endif

static __device__ __forceinline__ u16t f2bf(float f) {
  union { float f; unsigned u; } v; v.f = f;
  unsigned r = v.u + 0x7FFFu + ((v.u >> 16) & 1u);  // RNE
  return (u16t)(r >> 16);
}
// Pack two f32 -> two bf16 (round-half-up) in one v_perm: hi<<16 | lo.
static __device__ __forceinline__ unsigned pack2(float hi, float lo) {
  union { float f; unsigned u; } a, b; a.f = hi; b.f = lo;
  return __builtin_amdgcn_perm(a.u + 0x8000u, b.u + 0x8000u, 0x07060302u);
}

// XOR swizzle within a 64/128-elem row block: breaks 128B/256B bank period.
static __device__ __forceinline__ int swz(int row, int col) {
  return (((col >> 3) ^ (row & 7)) << 3) | (col & 7);
}

#define SEQ    2048
#define NHEAD  16
#define HDIM   64
#define DMODEL 1024

// ---------------------------------------------------------------------------
// All four W [1024][1024] f32 -> WT [n][k-swizzled] bf16 in one dispatch.
__global__ __launch_bounds__(256)
void wt_kernel(const float* __restrict__ W0, const float* __restrict__ W1,
               const float* __restrict__ W2, const float* __restrict__ W3,
               u16t* __restrict__ T0, u16t* __restrict__ T1,
               u16t* __restrict__ T2, u16t* __restrict__ T3) {
  int id = blockIdx.x * 256 + threadIdx.x;  // 2048 blocks -> 524288 ids
  int wsel = id >> 17;
  int r = id & 131071;
  int n = r & 1023;
  int k0 = (r >> 10) << 3;
  const float* W = wsel == 0 ? W0 : wsel == 1 ? W1 : wsel == 2 ? W2 : W3;
  u16t* T = wsel == 0 ? T0 : wsel == 1 ? T1 : wsel == 2 ? T2 : T3;
  const float* src = W + (size_t)k0 * 1024 + n;
  float f[8];
#pragma unroll
  for (int i = 0; i < 8; ++i) f[i] = src[(size_t)i * 1024];
  uint4 p;
  p.x = pack2(f[1], f[0]); p.y = pack2(f[3], f[2]);
  p.z = pack2(f[5], f[4]); p.w = pack2(f[7], f[6]);
  *(uint4*)&T[(size_t)n * 1024 + (k0 & ~63) + swz(n, k0 & 63)] = p;
}

// ---------------------------------------------------------------------------
// C[8192,1024] = A[8192,1024] * BT^T + bias   (BT pre-swizzled bf16)
// z=blockIdx.z selects the {A,BT,bias,C,scale} set (QK fusion).
// MODE 0: A fp32, out bf16 swizzled [b,h,s,d], post-scale qsc (ln2^-1 for Q)
// MODE 1: A bf16 swizzled via GLDS,  out fp32 flat [m,n]
// MODE 2: A fp32, out bf16 swizzled [b,h,d,s], row-scaled by sscv[bh][s]
template <int MODE>
__global__ __launch_bounds__(256)
void gemm_bt(const void* __restrict__ Ap0, const void* __restrict__ Ap1,
             const u16t* __restrict__ BT0, const u16t* __restrict__ BT1,
             const float* __restrict__ bias0, const float* __restrict__ bias1,
             void* __restrict__ Cp0, void* __restrict__ Cp1,
             float sc0, float sc1, const float* __restrict__ sscv) {
  constexpr int K = 1024;
  __shared__ __align__(16) u16t lA[128 * 64];
  __shared__ __align__(16) u16t lB[128 * 64];
  const int z = blockIdx.z;
  const void* Ap = z ? Ap1 : Ap0;
  const u16t* BT = z ? BT1 : BT0;
  const float* bias = z ? bias1 : bias0;
  void* Cp = z ? Cp1 : Cp0;
  const float qsc = z ? sc1 : sc0;
  const int tid = threadIdx.x;
  const int lane = tid & 63, w = tid >> 6;
  const int wm = w >> 1, wn = w & 1;
  const int lrow = lane & 15, lq = lane >> 4;
  const int m0 = blockIdx.y * 128, n0 = blockIdx.x * 128;

  floatx4 acc[4][4];
#pragma unroll
  for (int i = 0; i < 4; ++i)
#pragma unroll
    for (int j = 0; j < 4; ++j) acc[i][j] = {0.f, 0.f, 0.f, 0.f};

  for (int kb = 0; kb < K; kb += 64) {
    if constexpr (MODE == 1) {
      const u16t* Ag = (const u16t*)Ap;
#pragma unroll
      for (int i = 0; i < 4; ++i) {
        int chunk = w * 4 + i;
        int off = chunk * 1024 + lane * 16;  // byte offset in 16KB tile
        int r = off >> 7, ib = off & 127;
        GLDS16(Ag + (size_t)(m0 + r) * K + kb + (ib >> 1), &lA[chunk * 512]);
      }
    } else {
      const float* Ag = (const float*)Ap;
#pragma unroll
      for (int i = 0; i < 8; ++i) {
        int e = (i * 256 + tid) * 4;  // element in 128x64 tile
        int r = e >> 6, c = e & 63;
        const float* src = Ag + (size_t)(m0 + r) * K + kb + c;
        uint2 p;
        p.x = pack2(src[1], src[0]);
        p.y = pack2(src[3], src[2]);
        *(uint2*)&lA[r * 64 + swz(r, c)] = p;
      }
    }
#pragma unroll
    for (int i = 0; i < 4; ++i) {
      int chunk = w * 4 + i;
      int off = chunk * 1024 + lane * 16;
      int r = off >> 7, ib = off & 127;
      GLDS16(BT + (size_t)(n0 + r) * K + kb + (ib >> 1), &lB[chunk * 512]);
    }
    __syncthreads();
#pragma unroll
    for (int kk = 0; kk < 2; ++kk) {
      short8 af[4], bfr[4];
#pragma unroll
      for (int t = 0; t < 4; ++t) {
        int ar = wm * 64 + t * 16 + lrow;
        af[t] = *(const short8*)&lA[ar * 64 + swz(ar, kk * 32 + lq * 8)];
      }
#pragma unroll
      for (int t = 0; t < 4; ++t) {
        int br = wn * 64 + t * 16 + lrow;
        bfr[t] = *(const short8*)&lB[br * 64 + swz(br, kk * 32 + lq * 8)];
      }
#pragma unroll
      for (int i = 0; i < 4; ++i)
#pragma unroll
        for (int j = 0; j < 4; ++j)
          acc[i][j] = MFMA16(af[i], bfr[j], acc[i][j]);
    }
    __syncthreads();
  }

  float bvv[4];
#pragma unroll
  for (int j = 0; j < 4; ++j) bvv[j] = bias[n0 + wn * 64 + j * 16 + lrow];
  const int h = (n0 + wn * 64) >> 6;  // head (MODE 0/2): constant per wave
#pragma unroll
  for (int i = 0; i < 4; ++i) {
#pragma unroll
    for (int r = 0; r < 4; ++r) {
      int rg = m0 + wm * 64 + i * 16 + lq * 4 + r;  // C/D: row=(lane>>4)*4+reg
      int b = rg >> 11, s = rg & 2047;
      float rs;
      if constexpr (MODE == 2) rs = sscv[(size_t)(b * NHEAD + h) * SEQ + s];
      else                     rs = qsc;
#pragma unroll
      for (int j = 0; j < 4; ++j) {
        int cg = n0 + wn * 64 + j * 16 + lrow;
        float v = acc[i][j][r] + bvv[j];
        if constexpr (MODE == 1) {
          ((float*)Cp)[(size_t)rg * 1024 + cg] = v;
        } else {
          v *= rs;
          int d = cg & 63;
          size_t bh = (size_t)(b * NHEAD + h);
          if constexpr (MODE == 0)
            ((u16t*)Cp)[(bh * SEQ + s) * HDIM + swz(s, d)] = f2bf(v);
          else
            ((u16t*)Cp)[(bh * HDIM + d) * SEQ + (s & ~127) + swz(d, s & 127)] = f2bf(v);
        }
      }
    }
  }
}

// ---------------------------------------------------------------------------
// Column-softmax stats, exp2 domain, no max (S' bounded; see header):
//   ss[k] = 1 / (8 * sum_q 2^(S'[q,k])),  S' = Q' K^T with Q' = Q/ln2.
// Grid (16,64): block = 128 cols x full q; wave w owns cols [w*32, w*32+32).
__global__ __launch_bounds__(256)
void stats_kernel(const u16t* __restrict__ Qb, const u16t* __restrict__ Kb,
                  float* __restrict__ ss) {
  __shared__ __align__(16) u16t lK[128 * 64];
  __shared__ __align__(16) u16t lQ[128 * 64];
  const int tid = threadIdx.x, lane = tid & 63, w = tid >> 6;
  const int lrow = lane & 15, lq = lane >> 4;
  const int bh = blockIdx.y;
  const int c0 = blockIdx.x * 128;
  const u16t* Kbase = Kb + (size_t)bh * (SEQ * HDIM);
  const u16t* Qbase = Qb + (size_t)bh * (SEQ * HDIM);

#pragma unroll
  for (int i = 0; i < 4; ++i) {
    int chunk = w * 4 + i;
    GLDS16(Kbase + (size_t)c0 * HDIM + chunk * 512 + lane * 8, &lK[chunk * 512]);
  }

  short8 bfK[4];
  float lcur[2] = {0.f, 0.f};

  for (int q0 = 0; q0 < SEQ; q0 += 128) {
#pragma unroll
    for (int i = 0; i < 4; ++i) {
      int chunk = w * 4 + i;
      GLDS16(Qbase + (size_t)q0 * HDIM + chunk * 512 + lane * 8, &lQ[chunk * 512]);
    }
    __syncthreads();
    if (q0 == 0) {
#pragma unroll
      for (int nt = 0; nt < 2; ++nt) {
        int kr = w * 32 + nt * 16 + lrow;
        bfK[nt * 2]     = *(const short8*)&lK[kr * 64 + swz(kr, lq * 8)];
        bfK[nt * 2 + 1] = *(const short8*)&lK[kr * 64 + swz(kr, lq * 8 + 32)];
      }
    }
#pragma unroll
    for (int mt = 0; mt < 8; ++mt) {
      int qr = mt * 16 + lrow;
      short8 af0 = *(const short8*)&lQ[qr * 64 + swz(qr, lq * 8)];
      short8 af1 = *(const short8*)&lQ[qr * 64 + swz(qr, lq * 8 + 32)];
#pragma unroll
      for (int nt = 0; nt < 2; ++nt) {
        floatx4 a = {0.f, 0.f, 0.f, 0.f};
        a = MFMA16(af0, bfK[nt * 2], a);
        a = MFMA16(af1, bfK[nt * 2 + 1], a);
        lcur[nt] += EXP2(a[0]) + EXP2(a[1]) + EXP2(a[2]) + EXP2(a[3]);
      }
    }
    __syncthreads();
  }
  // lanes {l, l^16, l^32, l^48} hold disjoint q-subsets of the same column
#pragma unroll
  for (int t = 0; t < 2; ++t) {
    float ll = lcur[t];
    ll += __shfl_xor(ll, 16);
    ll += __shfl_xor(ll, 32);
    lcur[t] = ll;
  }
  if (lane < 16) {
#pragma unroll
    for (int t = 0; t < 2; ++t) {
      int col = c0 + w * 32 + t * 16 + lane;
      ss[(size_t)bh * SEQ + col] = 1.f / (8.f * lcur[t]);
    }
  }
}

// ---------------------------------------------------------------------------
// attn: per (b,h, 64-q tile): loop 128-k tiles:
//   S'^T = K*Q'^T (MFMA) -> P~ = 2^(S') packed via v_perm -> O += P~ * V'
// (V' pre-scaled by ss[k], so no stats loads and no muls here).
// LDS = 32KB exactly: Q staged through lKP once, frags kept in registers.
__global__ __launch_bounds__(256)
void attn_kernel(const u16t* __restrict__ Qb, const u16t* __restrict__ Kb,
                 const u16t* __restrict__ Vt, u16t* __restrict__ Hout) {
  __shared__ __align__(16) u16t lKP[128 * 64];  // Q stage -> K tile -> P tile
  __shared__ __align__(16) u16t lV[64 * 128];   // V'^T tile [d][k]
  const int tid = threadIdx.x, lane = tid & 63, w = tid >> 6;
  const int lrow = lane & 15, lq = lane >> 4;
  const int bh = blockIdx.y, q0 = blockIdx.x * 64;
  const size_t hb = (size_t)bh * (SEQ * HDIM);

  // Stage the 8KB Q tile through lKP, lift fragments to registers.
#pragma unroll
  for (int i = 0; i < 2; ++i) {
    int chunk = w * 2 + i;
    GLDS16(Qb + hb + (size_t)q0 * HDIM + chunk * 512 + lane * 8, &lKP[chunk * 512]);
  }
  __syncthreads();
  const int qr = w * 16 + lrow;
  short8 bq0 = *(const short8*)&lKP[qr * 64 + swz(qr, lq * 8)];
  short8 bq1 = *(const short8*)&lKP[qr * 64 + swz(qr, lq * 8 + 32)];
  __syncthreads();  // everyone has Q frags before K staging overwrites lKP

  floatx4 ao[4];
#pragma unroll
  for (int t = 0; t < 4; ++t) ao[t] = {0.f, 0.f, 0.f, 0.f};

  for (int kt = 0; kt < 16; ++kt) {
    const int k0 = kt * 128;
#pragma unroll
    for (int i = 0; i < 4; ++i) {
      int chunk = w * 4 + i;
      GLDS16(Kb + hb + (size_t)k0 * HDIM + chunk * 512 + lane * 8, &lKP[chunk * 512]);
    }
#pragma unroll
    for (int i = 0; i < 4; ++i) {
      int chunk = w * 4 + i;
      int off = chunk * 1024 + lane * 16;
      int d = off >> 8, ib = off & 255;
      GLDS16(Vt + hb + ((size_t)d << 11) + k0 + (ib >> 1), &lV[chunk * 512]);
    }
    __syncthreads();

    // S'^T = K Q'^T : lane holds St[k=nt*16+lq*4+r][q=w*16+lrow]
    floatx4 st[8];
#pragma unroll
    for (int nt = 0; nt < 8; ++nt) {
      int kr = nt * 16 + lrow;
      short8 ak0 = *(const short8*)&lKP[kr * 64 + swz(kr, lq * 8)];
      short8 ak1 = *(const short8*)&lKP[kr * 64 + swz(kr, lq * 8 + 32)];
      floatx4 a = {0.f, 0.f, 0.f, 0.f};
      a = MFMA16(ak0, bq0, a);
      a = MFMA16(ak1, bq1, a);
      st[nt] = a;
    }
    __syncthreads();  // all waves done reading lKP(K) before P overwrites it

    // P~[q][k] = 2^(S'): 4 k-consecutive vals -> 4 exp2 + 2 perm + b64 write
#pragma unroll
    for (int nt = 0; nt < 8; ++nt) {
      float p0 = EXP2(st[nt][0]);
      float p1 = EXP2(st[nt][1]);
      float p2 = EXP2(st[nt][2]);
      float p3 = EXP2(st[nt][3]);
      uint2 pk; pk.x = pack2(p1, p0); pk.y = pack2(p3, p2);
      *(uint2*)&lKP[qr * 128 + swz(qr, nt * 16 + lq * 4)] = pk;
    }
    // O += P~ * V' (wave reads only its own P rows -> no barrier needed)
    {
      short8 ap[4];
#pragma unroll
      for (int kk = 0; kk < 4; ++kk)
        ap[kk] = *(const short8*)&lKP[qr * 128 + swz(qr, kk * 32 + lq * 8)];
#pragma unroll
      for (int nt = 0; nt < 4; ++nt) {
        int vr = nt * 16 + lrow;
#pragma unroll
        for (int kk = 0; kk < 4; ++kk) {
          short8 bv = *(const short8*)&lV[vr * 128 + swz(vr, kk * 32 + lq * 8)];
          ao[nt] = MFMA16(ap[kk], bv, ao[nt]);
        }
      }
    }
    __syncthreads();  // before next iteration restages lKP/lV
  }

  // Hout[b][q][h*64+d], swizzled (key q&7) for gemm_bt<1>'s GLDS16 staging
  const int b = bh >> 4, h = bh & 15;
#pragma unroll
  for (int nt = 0; nt < 4; ++nt) {
    int d = nt * 16 + lrow;
#pragma unroll
    for (int r = 0; r < 4; ++r) {
      int q = q0 + w * 16 + lq * 4 + r;
      Hout[((size_t)b * SEQ + q) * DMODEL + h * HDIM + swz(q, d)] = f2bf(ao[nt][r]);
    }
  }
}

// ---------------------------------------------------------------------------
extern "C" void kernel_launch(void* const* d_in, const int* in_sizes, int n_in,
                              void* d_out, int out_size, void* d_ws, size_t ws_size,
                              hipStream_t stream) {
  (void)in_sizes; (void)n_in; (void)out_size; (void)ws_size;
  const float* queries = (const float*)d_in[0];
  const float* keys    = (const float*)d_in[1];
  const float* values  = (const float*)d_in[2];
  const float* Wq = (const float*)d_in[3];
  const float* bq = (const float*)d_in[4];
  const float* Wk = (const float*)d_in[5];
  const float* bk = (const float*)d_in[6];
  const float* Wv = (const float*)d_in[7];
  const float* bv = (const float*)d_in[8];
  const float* Wo = (const float*)d_in[9];
  const float* bo = (const float*)d_in[10];

  char* ws = (char*)d_ws;
  const size_t MB = 1024 * 1024;
  u16t* Qb   = (u16t*)(ws + 0 * MB);    // [b,h,s,d] bf16 swizzled (x 1/ln2)
  u16t* Kb   = (u16t*)(ws + 16 * MB);   // [b,h,s,d] bf16 swizzled
  u16t* Vt   = (u16t*)(ws + 32 * MB);   // [b,h,d,s] bf16 swizzled, ss-scaled
  u16t* Hout = (u16t*)(ws + 48 * MB);   // [b,s,dm] bf16 swizzled
  u16t* wqt  = (u16t*)(ws + 64 * MB);   // [n][k] bf16 swizzled, 2MB each
  u16t* wkt  = (u16t*)(ws + 66 * MB);
  u16t* wvt  = (u16t*)(ws + 68 * MB);
  u16t* wot  = (u16t*)(ws + 70 * MB);
  float* ssc = (float*)(ws + 72 * MB);  // [bh][s] 1/(8*sum 2^S')

  wt_kernel<<<2048, 256, 0, stream>>>(Wq, Wk, Wv, Wo, wqt, wkt, wvt, wot);

  gemm_bt<0><<<dim3(8, 64, 2), 256, 0, stream>>>(
      queries, keys, wqt, wkt, bq, bk, Qb, Kb, 1.44269504f, 1.0f, nullptr);

  stats_kernel<<<dim3(16, 64), 256, 0, stream>>>(Qb, Kb, ssc);

  gemm_bt<2><<<dim3(8, 64, 1), 256, 0, stream>>>(
      values, values, wvt, wvt, bv, bv, Vt, Vt, 1.0f, 1.0f, ssc);

  attn_kernel<<<dim3(32, 64), 256, 0, stream>>>(Qb, Kb, Vt, Hout);

  gemm_bt<1><<<dim3(8, 64, 1), 256, 0, stream>>>(
      Hout, Hout, wot, wot, bo, bo, d_out, d_out, 1.0f, 1.0f, nullptr);
}